// Round 2
// baseline (645.744 us; speedup 1.0000x reference)
//
#include <hip/hip_runtime.h>

typedef float v4f __attribute__((ext_vector_type(4)));

// Problem constants
#define B_ 128
#define T_ 197
#define D_ 768
#define E_ 8
#define R_ 8
#define O_ 2304

// d_out flat layout (fp32 elements), in reference return order
#define NWU      (128LL * 197LL * 2304LL)      // weighted_update
#define OFF_RL   (NWU)                          // router_logits: 128*8
#define OFF_SEL  (OFF_RL + 1024LL)              // selected_experts: 128 (as float)
#define OFF_EW   (OFF_SEL + 128LL)              // expert_weights: 128*8
#define OFF_IMP  (OFF_EW + 1024LL)              // importance: 8
#define OFF_LOAD (OFF_IMP + 8LL)                // load: 8

// ---------------------------------------------------------------------------
// Kernel 1: partial token sums over T-chunks, float4-vectorized.
// partials live in the WU region of d_out (consumed by `route` before
// fused_lora overwrites the region).  part[(b*4+c)*768 + d]
// Also zero-inits the importance/load accumulators (16 floats) so `route`
// can atomically accumulate into them (stream order guarantees visibility).
// ---------------------------------------------------------------------------
__global__ void pool_partial(const float* __restrict__ tokens,
                             float* __restrict__ out) {
    int c   = blockIdx.x;          // 0..3
    int b   = blockIdx.y;          // 0..127
    int tid = threadIdx.x;         // 0..191  (float4 column)
    if (c == 0 && b == 0 && tid < 16) out[OFF_IMP + tid] = 0.0f;
    int t0 = c * 50;
    int t1 = t0 + 50; if (t1 > T_) t1 = T_;
    const float4* tp = (const float4*)(tokens + (long long)b * T_ * D_);
    float4 acc; acc.x = 0.f; acc.y = 0.f; acc.z = 0.f; acc.w = 0.f;
    for (int t = t0; t < t1; ++t) {
        float4 v = tp[t * 192 + tid];
        acc.x += v.x; acc.y += v.y; acc.z += v.z; acc.w += v.w;
    }
    ((float4*)out)[(long long)(b * 4 + c) * 192 + tid] = acc;
}

// ---------------------------------------------------------------------------
// Kernel 2: routing + stats.  One block per batch row.
// stats (importance/load) folded in via device-scope atomicAdd.
// ---------------------------------------------------------------------------
__global__ void route(const float* __restrict__ part,
                      const float* __restrict__ w_gate,
                      float* __restrict__ out) {
    __shared__ float pooled[768];
    __shared__ float psum[64];
    __shared__ float logits[8];
    __shared__ int   sel_s;
    __shared__ float top1_s;
    __shared__ float m_s, inv_s;

    int b   = blockIdx.x;
    int tid = threadIdx.x;

    #pragma unroll
    for (int j = 0; j < 3; ++j) {
        int d = tid + j * 256;
        float s = part[(long long)(b * 4 + 0) * D_ + d]
                + part[(long long)(b * 4 + 1) * D_ + d]
                + part[(long long)(b * 4 + 2) * D_ + d]
                + part[(long long)(b * 4 + 3) * D_ + d];
        pooled[d] = s * (1.0f / 197.0f);
    }
    __syncthreads();

    if (tid < 64) {
        int e = tid & 7;
        int p = tid >> 3;
        float s = 0.f;
        int d0 = p * 96;
        for (int d = d0; d < d0 + 96; ++d) s += pooled[d] * w_gate[d * 8 + e];
        psum[tid] = s;
    }
    __syncthreads();

    if (tid < 8) {
        float s = 0.f;
        #pragma unroll
        for (int p = 0; p < 8; ++p) s += psum[p * 8 + tid];
        logits[tid] = s;
        out[OFF_RL + (long long)b * 8 + tid] = s;
    }
    __syncthreads();

    if (tid == 0) {
        float m = logits[0];
        int sel = 0;
        #pragma unroll
        for (int e = 1; e < 8; ++e)
            if (logits[e] > m) { m = logits[e]; sel = e; }   // first max wins
        float den = 0.f;
        #pragma unroll
        for (int e = 0; e < 8; ++e) den += expf(logits[e] - m);
        float t1v = 1.0f / den;
        sel_s  = sel;
        top1_s = t1v;
        m_s    = m;
        inv_s  = t1v;
        out[OFF_SEL + b] = (float)sel;
        atomicAdd(&out[OFF_IMP + sel], t1v);     // importance[sel] += top1
    }
    __syncthreads();

    if (tid < 8) {
        out[OFF_EW + (long long)b * 8 + tid] = (tid == sel_s) ? top1_s : 0.0f;
        // load[e] += softmax(logits)[e]
        atomicAdd(&out[OFF_LOAD + tid], expf(logits[tid] - m_s) * inv_s);
    }
}

// ---------------------------------------------------------------------------
// Kernel 3: fused  h = (tokens @ A[sel]) * gs  →  LDS  →  wu = h @ Bw[sel].
//
// Round-2 restructure: occupancy over LDS capacity.
//  - Bw is NOT staged in LDS.  lora_b is 590 KB total → L2-resident; phase-3
//    reads it as 1 KB/wave coalesced bursts (L2 hits).  LDS drops 75 KB →
//    25 KB, __launch_bounds__(256,4) → 16 waves/CU (was 8).
//  - Grid 1024 blocks (8 chunks × 25 rows) so 4 blocks/CU are resident and
//    token-read / WU-write phases overlap across blocks.
//  - No barrier between phase 1 and phase 3: each wave's h rows are
//    wave-private (lane-0 LDS write, same-wave read; lgkmcnt handles it).
//    Only one __syncthreads (after A staging) — waves run free after it.
//  - A^T stays in LDS (24 KB): 64-lane × row reuse; round-1 history showed
//    a 614 MB HBM refetch when A came from global.
// ---------------------------------------------------------------------------
__global__ void __launch_bounds__(256, 4)
fused_lora(const float* __restrict__ tokens,
           const float* __restrict__ lora_a,
           const float* __restrict__ lora_b,
           const float* __restrict__ scaling,
           const float* __restrict__ outc,
           float* __restrict__ out) {
    __shared__ __align__(16) float As[8 * 768];   // 24 KB, transposed A
    __shared__ __align__(16) float h_s[25 * 8];   // 800 B

    int chunk = blockIdx.x;        // 0..7
    int b     = blockIdx.y;        // 0..127
    int tid   = threadIdx.x;

    int   sel  = (int)outc[OFF_SEL + b];
    float top1 = outc[OFF_EW + (long long)b * 8 + sel];
    float gs   = scaling[sel] * top1;

    // ---- Phase 0: stage A[sel] ([d][r] layout) transposed into As[r][d].
    const float4* A4 = (const float4*)(lora_a + (long long)sel * 768 * 8);
    for (int f = tid; f < 1536; f += 256) {
        float4 g = A4[f];
        int d  = f >> 1;
        int r0 = (f & 1) * 4;
        As[(r0 + 0) * 768 + d] = g.x;
        As[(r0 + 1) * 768 + d] = g.y;
        As[(r0 + 2) * 768 + d] = g.z;
        As[(r0 + 3) * 768 + d] = g.w;
    }
    __syncthreads();

    int wave = tid >> 6;
    int lane = tid & 63;
    int t0 = chunk * 25;
    int t1 = t0 + 25; if (t1 > T_) t1 = T_;
    int nrows = t1 - t0;
    int rpw = (nrows + 3) >> 2;
    int ts  = t0 + wave * rpw;
    int te  = ts + rpw; if (te > t1) te = t1;

    // ---- Phase 1: h rows → LDS (wave-per-row, shuffle reduce)
    for (int t = ts; t < te; ++t) {
        const float4* tok4 = (const float4*)(tokens + ((long long)b * T_ + t) * D_);
        float acc[8];
        #pragma unroll
        for (int r = 0; r < 8; ++r) acc[r] = 0.f;

        #pragma unroll
        for (int k = 0; k < 3; ++k) {
            int d4 = lane + 64 * k;
            float4 tv = tok4[d4];
            #pragma unroll
            for (int r = 0; r < 8; ++r) {
                float4 ar = *(const float4*)(As + r * 768 + d4 * 4);
                acc[r] += tv.x * ar.x + tv.y * ar.y + tv.z * ar.z + tv.w * ar.w;
            }
        }

        #pragma unroll
        for (int off = 32; off > 0; off >>= 1) {
            #pragma unroll
            for (int r = 0; r < 8; ++r)
                acc[r] += __shfl_xor(acc[r], off, 64);
        }

        if (lane == 0) {
            #pragma unroll
            for (int r = 0; r < 8; ++r) h_s[(t - t0) * 8 + r] = acc[r] * gs;
        }
    }
    // NO __syncthreads: h rows are wave-private.

    // ---- Phase 3: weighted_update, 4 rows per pass, Bw from global (L2).
    const float4* Bwg = (const float4*)(lora_b + (long long)sel * 8 * 2304);

    for (int tb = ts; tb < te; tb += 4) {
        int nr = te - tb; if (nr > 4) nr = 4;

        float hreg[4][8];
        #pragma unroll
        for (int r = 0; r < 4; ++r) {
            if (r < nr) {
                #pragma unroll
                for (int j = 0; j < 8; ++j)
                    hreg[r][j] = h_s[(tb - t0 + r) * 8 + j];
            }
        }

        #pragma unroll
        for (int k = 0; k < 9; ++k) {
            int o4 = lane + 64 * k;
            v4f accv[4];
            #pragma unroll
            for (int r = 0; r < 4; ++r) {
                accv[r].x = 0.f; accv[r].y = 0.f; accv[r].z = 0.f; accv[r].w = 0.f;
            }
            #pragma unroll
            for (int j = 0; j < 8; ++j) {
                float4 bvf = Bwg[j * 576 + o4];
                v4f bv; bv.x = bvf.x; bv.y = bvf.y; bv.z = bvf.z; bv.w = bvf.w;
                #pragma unroll
                for (int r = 0; r < 4; ++r) {
                    if (r < nr) accv[r] += hreg[r][j] * bv;
                }
            }
            #pragma unroll
            for (int r = 0; r < 4; ++r) {
                if (r < nr) {
                    v4f* outrow = (v4f*)(out + ((long long)b * T_ + (tb + r)) * O_);
                    __builtin_nontemporal_store(accv[r], &outrow[o4]);
                }
            }
        }
    }
}

// ---------------------------------------------------------------------------
extern "C" void kernel_launch(void* const* d_in, const int* in_sizes, int n_in,
                              void* d_out, int out_size, void* d_ws, size_t ws_size,
                              hipStream_t stream) {
    const float* tokens  = (const float*)d_in[0];
    const float* w_gate  = (const float*)d_in[1];
    const float* lora_a  = (const float*)d_in[2];
    const float* lora_b  = (const float*)d_in[3];
    const float* scaling = (const float*)d_in[4];
    float* out = (float*)d_out;

    pool_partial<<<dim3(4, 128), 192, 0, stream>>>(tokens, out);
    route<<<128, 256, 0, stream>>>(out, w_gate, out);
    fused_lora<<<dim3(8, 128), 256, 0, stream>>>(tokens, lora_a, lora_b, scaling, out, out);
}

// Round 3
// 557.018 us; speedup vs baseline: 1.1593x; 1.1593x over previous
//
#include <hip/hip_runtime.h>

typedef float v4f __attribute__((ext_vector_type(4)));

// Problem constants
#define B_ 128
#define T_ 197
#define D_ 768
#define E_ 8
#define R_ 8
#define O_ 2304

// d_out flat layout (fp32 elements), in reference return order
#define NWU      (128LL * 197LL * 2304LL)      // weighted_update
#define OFF_RL   (NWU)                          // router_logits: 128*8
#define OFF_SEL  (OFF_RL + 1024LL)              // selected_experts: 128 (as float)
#define OFF_EW   (OFF_SEL + 128LL)              // expert_weights: 128*8
#define OFF_IMP  (OFF_EW + 1024LL)              // importance: 8
#define OFF_LOAD (OFF_IMP + 8LL)                // load: 8

// ---------------------------------------------------------------------------
// Kernel 1: partial token sums over T-chunks, float4-vectorized.
// partials live in the WU region of d_out (consumed by `route` before
// fused_lora overwrites the region).  part[(b*4+c)*768 + d]
// Also zero-inits the importance/load accumulators (16 floats) so `route`
// can atomically accumulate into them (stream order guarantees visibility).
// ---------------------------------------------------------------------------
__global__ void pool_partial(const float* __restrict__ tokens,
                             float* __restrict__ out) {
    int c   = blockIdx.x;          // 0..3
    int b   = blockIdx.y;          // 0..127
    int tid = threadIdx.x;         // 0..191  (float4 column)
    if (c == 0 && b == 0 && tid < 16) out[OFF_IMP + tid] = 0.0f;
    int t0 = c * 50;
    int t1 = t0 + 50; if (t1 > T_) t1 = T_;
    const float4* tp = (const float4*)(tokens + (long long)b * T_ * D_);
    float4 acc; acc.x = 0.f; acc.y = 0.f; acc.z = 0.f; acc.w = 0.f;
    for (int t = t0; t < t1; ++t) {
        float4 v = tp[t * 192 + tid];
        acc.x += v.x; acc.y += v.y; acc.z += v.z; acc.w += v.w;
    }
    ((float4*)out)[(long long)(b * 4 + c) * 192 + tid] = acc;
}

// ---------------------------------------------------------------------------
// Kernel 2: routing + stats.  One block per batch row.
// stats (importance/load) folded in via device-scope atomicAdd.
// ---------------------------------------------------------------------------
__global__ void route(const float* __restrict__ part,
                      const float* __restrict__ w_gate,
                      float* __restrict__ out) {
    __shared__ float pooled[768];
    __shared__ float psum[64];
    __shared__ float logits[8];
    __shared__ int   sel_s;
    __shared__ float top1_s;
    __shared__ float m_s, inv_s;

    int b   = blockIdx.x;
    int tid = threadIdx.x;

    #pragma unroll
    for (int j = 0; j < 3; ++j) {
        int d = tid + j * 256;
        float s = part[(long long)(b * 4 + 0) * D_ + d]
                + part[(long long)(b * 4 + 1) * D_ + d]
                + part[(long long)(b * 4 + 2) * D_ + d]
                + part[(long long)(b * 4 + 3) * D_ + d];
        pooled[d] = s * (1.0f / 197.0f);
    }
    __syncthreads();

    if (tid < 64) {
        int e = tid & 7;
        int p = tid >> 3;
        float s = 0.f;
        int d0 = p * 96;
        for (int d = d0; d < d0 + 96; ++d) s += pooled[d] * w_gate[d * 8 + e];
        psum[tid] = s;
    }
    __syncthreads();

    if (tid < 8) {
        float s = 0.f;
        #pragma unroll
        for (int p = 0; p < 8; ++p) s += psum[p * 8 + tid];
        logits[tid] = s;
        out[OFF_RL + (long long)b * 8 + tid] = s;
    }
    __syncthreads();

    if (tid == 0) {
        float m = logits[0];
        int sel = 0;
        #pragma unroll
        for (int e = 1; e < 8; ++e)
            if (logits[e] > m) { m = logits[e]; sel = e; }   // first max wins
        float den = 0.f;
        #pragma unroll
        for (int e = 0; e < 8; ++e) den += expf(logits[e] - m);
        float t1v = 1.0f / den;
        sel_s  = sel;
        top1_s = t1v;
        m_s    = m;
        inv_s  = t1v;
        out[OFF_SEL + b] = (float)sel;
        atomicAdd(&out[OFF_IMP + sel], t1v);     // importance[sel] += top1
    }
    __syncthreads();

    if (tid < 8) {
        out[OFF_EW + (long long)b * 8 + tid] = (tid == sel_s) ? top1_s : 0.0f;
        // load[e] += softmax(logits)[e]
        atomicAdd(&out[OFF_LOAD + tid], expf(logits[tid] - m_s) * inv_s);
    }
}

// ---------------------------------------------------------------------------
// Kernel 3: fused  h = (tokens @ A[sel]) * gs  →  regs  →  wu = h @ Bw[sel].
//
// Round-3 structure: round-1's traffic + round-2's overlap.
//  - Bw staged ONCE per block in LDS (72 KB).  Round 2 proved reading Bw
//    from "L2-resident" global is a lie under streaming pressure:
//    FETCH +295 MB, WRITE +292 MB, 2.4× slower.
//  - A[sel] in REGISTERS (24 float4/lane = 96 VGPR; 24 KB total, L1-hot
//    across the block's 4 waves).  Removes the A^T-in-LDS overlay that
//    forced the all-h-then-all-WU phase separation in round 1.
//  - h in registers: the __shfl_xor butterfly leaves the full sum in EVERY
//    lane, so no h_s LDS round-trip and no broadcast barrier.
//  - Per-wave 4-row pipeline: compute h for 4 rows (12 KB token reads),
//    immediately write those 4 WU rows (36 KB NT stores).  After the single
//    staging barrier, every wave interleaves read and write traffic —
//    both HBM directions busy at once.  4-row batching keeps Bw LDS reads
//    at 18 float4/row/lane.
// ---------------------------------------------------------------------------
__global__ void __launch_bounds__(256, 2)
fused_lora(const float* __restrict__ tokens,
           const float* __restrict__ lora_a,
           const float* __restrict__ lora_b,
           const float* __restrict__ scaling,
           const float* __restrict__ outc,
           float* __restrict__ out) {
    __shared__ __align__(16) float Bw_s[8 * 2304];   // 72 KB

    int chunk = blockIdx.x;        // 0..3
    int b     = blockIdx.y;        // 0..127
    int tid   = threadIdx.x;
    int lane  = tid & 63;
    int wave  = tid >> 6;

    int   sel  = (int)outc[OFF_SEL + b];
    float top1 = outc[OFF_EW + (long long)b * 8 + sel];
    float gs   = scaling[sel] * top1;

    // ---- Stage Bw[sel] (72 KB) into LDS, coalesced.
    const float4* Bw4g = (const float4*)(lora_b + (long long)sel * 8 * 2304);
    float4*       Bw4s = (float4*)Bw_s;
    for (int i = tid; i < 4608; i += 256) Bw4s[i] = Bw4g[i];

    // ---- Load this lane's A slice into registers.
    // A layout [d][r]; lane owns d = (lane+64k)*4+i for k=0..2, i=0..3.
    // Alo[k][i] = A[d][0..3], Ahi[k][i] = A[d][4..7].
    const float4* A4g = (const float4*)(lora_a + (long long)sel * (D_ * R_));
    v4f Alo[3][4], Ahi[3][4];
    #pragma unroll
    for (int k = 0; k < 3; ++k) {
        #pragma unroll
        for (int i = 0; i < 4; ++i) {
            int d = (lane + 64 * k) * 4 + i;
            float4 x0 = A4g[d * 2 + 0];
            float4 x1 = A4g[d * 2 + 1];
            Alo[k][i].x = x0.x; Alo[k][i].y = x0.y; Alo[k][i].z = x0.z; Alo[k][i].w = x0.w;
            Ahi[k][i].x = x1.x; Ahi[k][i].y = x1.y; Ahi[k][i].z = x1.z; Ahi[k][i].w = x1.w;
        }
    }
    __syncthreads();   // Bw_s ready; only barrier in the kernel.

    int t0 = chunk * 50;
    int t1 = t0 + 50; if (t1 > T_) t1 = T_;
    int nrows = t1 - t0;
    int rpw = (nrows + 3) >> 2;
    int ts  = t0 + wave * rpw;
    int te  = ts + rpw; if (te > t1) te = t1;

    for (int tb = ts; tb < te; tb += 4) {
        int nr = te - tb; if (nr > 4) nr = 4;   // wave-uniform

        // ---- h for up to 4 rows; butterfly gives every lane the sums.
        float hreg[4][8];
        #pragma unroll
        for (int r = 0; r < 4; ++r) {
            if (r < nr) {   // wave-uniform guard: shuffles are safe inside
                const float4* tok4 =
                    (const float4*)(tokens + ((long long)b * T_ + (tb + r)) * D_);
                v4f a03; a03.x = 0.f; a03.y = 0.f; a03.z = 0.f; a03.w = 0.f;
                v4f a47 = a03;
                #pragma unroll
                for (int k = 0; k < 3; ++k) {
                    float4 tv = tok4[lane + 64 * k];
                    a03 += tv.x * Alo[k][0]; a47 += tv.x * Ahi[k][0];
                    a03 += tv.y * Alo[k][1]; a47 += tv.y * Ahi[k][1];
                    a03 += tv.z * Alo[k][2]; a47 += tv.z * Ahi[k][2];
                    a03 += tv.w * Alo[k][3]; a47 += tv.w * Ahi[k][3];
                }
                float sh[8] = { a03.x, a03.y, a03.z, a03.w,
                                a47.x, a47.y, a47.z, a47.w };
                #pragma unroll
                for (int off = 32; off > 0; off >>= 1) {
                    #pragma unroll
                    for (int j = 0; j < 8; ++j)
                        sh[j] += __shfl_xor(sh[j], off, 64);
                }
                #pragma unroll
                for (int j = 0; j < 8; ++j) hreg[r][j] = sh[j] * gs;
            }
        }

        // ---- WU for the same rows: one pass over Bw in LDS, 4 rows deep.
        #pragma unroll
        for (int k = 0; k < 9; ++k) {
            int o4 = lane + 64 * k;
            v4f acc0, acc1, acc2, acc3;
            acc0.x = 0.f; acc0.y = 0.f; acc0.z = 0.f; acc0.w = 0.f;
            acc1 = acc0; acc2 = acc0; acc3 = acc0;
            #pragma unroll
            for (int j = 0; j < 8; ++j) {
                v4f bv = ((const v4f*)Bw_s)[j * 576 + o4];
                acc0 += hreg[0][j] * bv;
                acc1 += hreg[1][j] * bv;
                acc2 += hreg[2][j] * bv;
                acc3 += hreg[3][j] * bv;
            }
            {
                v4f* o0 = (v4f*)(out + ((long long)b * T_ + (tb + 0)) * O_);
                __builtin_nontemporal_store(acc0, &o0[o4]);
            }
            if (nr > 1) {
                v4f* o1 = (v4f*)(out + ((long long)b * T_ + (tb + 1)) * O_);
                __builtin_nontemporal_store(acc1, &o1[o4]);
            }
            if (nr > 2) {
                v4f* o2 = (v4f*)(out + ((long long)b * T_ + (tb + 2)) * O_);
                __builtin_nontemporal_store(acc2, &o2[o4]);
            }
            if (nr > 3) {
                v4f* o3 = (v4f*)(out + ((long long)b * T_ + (tb + 3)) * O_);
                __builtin_nontemporal_store(acc3, &o3[o4]);
            }
        }
    }
}

// ---------------------------------------------------------------------------
extern "C" void kernel_launch(void* const* d_in, const int* in_sizes, int n_in,
                              void* d_out, int out_size, void* d_ws, size_t ws_size,
                              hipStream_t stream) {
    const float* tokens  = (const float*)d_in[0];
    const float* w_gate  = (const float*)d_in[1];
    const float* lora_a  = (const float*)d_in[2];
    const float* lora_b  = (const float*)d_in[3];
    const float* scaling = (const float*)d_in[4];
    float* out = (float*)d_out;

    pool_partial<<<dim3(4, 128), 192, 0, stream>>>(tokens, out);
    route<<<128, 256, 0, stream>>>(out, w_gate, out);
    fused_lora<<<dim3(4, 128), 256, 0, stream>>>(tokens, lora_a, lora_b, scaling, out, out);
}

// Round 4
// 338.389 us; speedup vs baseline: 1.9083x; 1.6461x over previous
//
#include <hip/hip_runtime.h>

typedef float v4f __attribute__((ext_vector_type(4)));

// Problem constants
#define B_ 128
#define T_ 197
#define D_ 768
#define E_ 8
#define R_ 8
#define O_ 2304

// d_out flat layout (fp32 elements), in reference return order
#define NWU      (128LL * 197LL * 2304LL)      // weighted_update
#define OFF_RL   (NWU)                          // router_logits: 128*8
#define OFF_SEL  (OFF_RL + 1024LL)              // selected_experts: 128 (as float)
#define OFF_EW   (OFF_SEL + 128LL)              // expert_weights: 128*8
#define OFF_IMP  (OFF_EW + 1024LL)              // importance: 8
#define OFF_LOAD (OFF_IMP + 8LL)                // load: 8

// ---------------------------------------------------------------------------
// Kernel 1: partial token sums over T-chunks, float4-vectorized.
// partials live in the WU region of d_out (consumed by `route` before
// fused_lora overwrites the region).  part[(b*4+c)*768 + d]
// Also zero-inits the importance/load accumulators (16 floats).
// ---------------------------------------------------------------------------
__global__ void pool_partial(const float* __restrict__ tokens,
                             float* __restrict__ out) {
    int c   = blockIdx.x;          // 0..3
    int b   = blockIdx.y;          // 0..127
    int tid = threadIdx.x;         // 0..191  (float4 column)
    if (c == 0 && b == 0 && tid < 16) out[OFF_IMP + tid] = 0.0f;
    int t0 = c * 50;
    int t1 = t0 + 50; if (t1 > T_) t1 = T_;
    const float4* tp = (const float4*)(tokens + (long long)b * T_ * D_);
    float4 acc; acc.x = 0.f; acc.y = 0.f; acc.z = 0.f; acc.w = 0.f;
    for (int t = t0; t < t1; ++t) {
        float4 v = tp[t * 192 + tid];
        acc.x += v.x; acc.y += v.y; acc.z += v.z; acc.w += v.w;
    }
    ((float4*)out)[(long long)(b * 4 + c) * 192 + tid] = acc;
}

// ---------------------------------------------------------------------------
// Kernel 2: routing + stats.  One block per batch row.
// stats (importance/load) folded in via device-scope atomicAdd.
// ---------------------------------------------------------------------------
__global__ void route(const float* __restrict__ part,
                      const float* __restrict__ w_gate,
                      float* __restrict__ out) {
    __shared__ float pooled[768];
    __shared__ float psum[64];
    __shared__ float logits[8];
    __shared__ int   sel_s;
    __shared__ float top1_s;
    __shared__ float m_s, inv_s;

    int b   = blockIdx.x;
    int tid = threadIdx.x;

    #pragma unroll
    for (int j = 0; j < 3; ++j) {
        int d = tid + j * 256;
        float s = part[(long long)(b * 4 + 0) * D_ + d]
                + part[(long long)(b * 4 + 1) * D_ + d]
                + part[(long long)(b * 4 + 2) * D_ + d]
                + part[(long long)(b * 4 + 3) * D_ + d];
        pooled[d] = s * (1.0f / 197.0f);
    }
    __syncthreads();

    if (tid < 64) {
        int e = tid & 7;
        int p = tid >> 3;
        float s = 0.f;
        int d0 = p * 96;
        for (int d = d0; d < d0 + 96; ++d) s += pooled[d] * w_gate[d * 8 + e];
        psum[tid] = s;
    }
    __syncthreads();

    if (tid < 8) {
        float s = 0.f;
        #pragma unroll
        for (int p = 0; p < 8; ++p) s += psum[p * 8 + tid];
        logits[tid] = s;
        out[OFF_RL + (long long)b * 8 + tid] = s;
    }
    __syncthreads();

    if (tid == 0) {
        float m = logits[0];
        int sel = 0;
        #pragma unroll
        for (int e = 1; e < 8; ++e)
            if (logits[e] > m) { m = logits[e]; sel = e; }   // first max wins
        float den = 0.f;
        #pragma unroll
        for (int e = 0; e < 8; ++e) den += expf(logits[e] - m);
        float t1v = 1.0f / den;
        sel_s  = sel;
        top1_s = t1v;
        m_s    = m;
        inv_s  = t1v;
        out[OFF_SEL + b] = (float)sel;
        atomicAdd(&out[OFF_IMP + sel], t1v);     // importance[sel] += top1
    }
    __syncthreads();

    if (tid < 8) {
        out[OFF_EW + (long long)b * 8 + tid] = (tid == sel_s) ? top1_s : 0.0f;
        // load[e] += softmax(logits)[e]
        atomicAdd(&out[OFF_LOAD + tid], expf(logits[tid] - m_s) * inv_s);
    }
}

// ---------------------------------------------------------------------------
// Kernel 3: fused  h = (tokens @ A[sel]) * gs  →  regs  →  wu = h @ Bw[sel].
//
// Round-4 structure: A^T and Bw CO-RESIDENT in LDS, 512-thread blocks.
//  - 96 KB LDS (As 24 KB + Bw 72 KB) → 1 block/CU, 8 waves/CU (same wave
//    count round 1 actually achieved, without the A/Bw overlay that forced
//    its phase serialization).
//  - Round 3's lesson: A-in-registers (96 VGPR) spilled at the 128-VGPR
//    cap → 368 MB of scratch FETCH.  A stays in LDS; live state ~90 VGPR.
//  - h in registers: __shfl_xor butterfly leaves sums in EVERY lane; no
//    h LDS round-trip, no barrier after staging.
//  - Per-wave 4-row pipeline: compute h for 4 rows (token reads), write
//    those 4 WU rows (NT stores) — each wave interleaves HBM reads and
//    writes, so both directions stay busy (fill kernel proves ~10%
//    occupancy saturates the write pipe when stores are contiguous).
//  - Rows round-robin per wave (stride 8) for load balance across the
//    47-row tail chunk.
// ---------------------------------------------------------------------------
__global__ void __launch_bounds__(512, 2)
fused_lora(const float* __restrict__ tokens,
           const float* __restrict__ lora_a,
           const float* __restrict__ lora_b,
           const float* __restrict__ scaling,
           const float* __restrict__ outc,
           float* __restrict__ out) {
    __shared__ __align__(16) float Bw_s[8 * 2304];   // 72 KB
    __shared__ __align__(16) float As[8 * 768];      // 24 KB, transposed A

    int chunk = blockIdx.x;        // 0..3
    int b     = blockIdx.y;        // 0..127
    int tid   = threadIdx.x;       // 0..511
    int lane  = tid & 63;
    int wave  = tid >> 6;          // 0..7

    int   sel  = (int)outc[OFF_SEL + b];
    float top1 = outc[OFF_EW + (long long)b * 8 + sel];
    float gs   = scaling[sel] * top1;

    // ---- Stage Bw[sel] (72 KB) into LDS, coalesced.
    const float4* Bw4g = (const float4*)(lora_b + (long long)sel * 8 * 2304);
    float4*       Bw4s = (float4*)Bw_s;
    for (int i = tid; i < 4608; i += 512) Bw4s[i] = Bw4g[i];

    // ---- Stage A[sel] ([d][r] layout) transposed into As[r][d].
    const float4* A4 = (const float4*)(lora_a + (long long)sel * 768 * 8);
    for (int f = tid; f < 1536; f += 512) {
        float4 g = A4[f];
        int d  = f >> 1;
        int r0 = (f & 1) * 4;
        As[(r0 + 0) * 768 + d] = g.x;
        As[(r0 + 1) * 768 + d] = g.y;
        As[(r0 + 2) * 768 + d] = g.z;
        As[(r0 + 3) * 768 + d] = g.w;
    }
    __syncthreads();   // only barrier in the kernel

    int t0 = chunk * 50;
    int t1 = t0 + 50; if (t1 > T_) t1 = T_;

    // Wave w owns rows t0+w, t0+w+8, t0+w+16, ...  Process 4 at a time.
    for (int tg0 = t0 + wave; tg0 < t1; tg0 += 32) {
        int nr = (t1 - tg0 + 7) >> 3;          // valid rows in this group
        if (nr > 4) nr = 4;                    // wave-uniform

        // ---- h for up to 4 rows; butterfly gives every lane the sums.
        float hreg[4][8];
        #pragma unroll
        for (int r = 0; r < 4; ++r) {
            if (r < nr) {   // wave-uniform: shuffles safe inside
                int t = tg0 + 8 * r;
                const float4* tok4 =
                    (const float4*)(tokens + ((long long)b * T_ + t) * D_);
                float acc[8];
                #pragma unroll
                for (int j = 0; j < 8; ++j) acc[j] = 0.f;
                #pragma unroll
                for (int k = 0; k < 3; ++k) {
                    int d4 = lane + 64 * k;
                    float4 tv = tok4[d4];
                    #pragma unroll
                    for (int j = 0; j < 8; ++j) {
                        v4f ar = *(const v4f*)(As + j * 768 + d4 * 4);
                        acc[j] += tv.x * ar.x + tv.y * ar.y
                                + tv.z * ar.z + tv.w * ar.w;
                    }
                }
                #pragma unroll
                for (int off = 32; off > 0; off >>= 1) {
                    #pragma unroll
                    for (int j = 0; j < 8; ++j)
                        acc[j] += __shfl_xor(acc[j], off, 64);
                }
                #pragma unroll
                for (int j = 0; j < 8; ++j) hreg[r][j] = acc[j] * gs;
            }
        }

        // ---- WU for the same rows: one pass over Bw in LDS, 4 rows deep.
        #pragma unroll
        for (int k = 0; k < 9; ++k) {
            int o4 = lane + 64 * k;
            v4f acc0, acc1, acc2, acc3;
            acc0.x = 0.f; acc0.y = 0.f; acc0.z = 0.f; acc0.w = 0.f;
            acc1 = acc0; acc2 = acc0; acc3 = acc0;
            #pragma unroll
            for (int j = 0; j < 8; ++j) {
                v4f bv = ((const v4f*)Bw_s)[j * 576 + o4];
                acc0 += hreg[0][j] * bv;
                acc1 += hreg[1][j] * bv;
                acc2 += hreg[2][j] * bv;
                acc3 += hreg[3][j] * bv;
            }
            {
                v4f* o0 = (v4f*)(out + ((long long)b * T_ + (tg0 + 0)) * O_);
                __builtin_nontemporal_store(acc0, &o0[o4]);
            }
            if (nr > 1) {
                v4f* o1 = (v4f*)(out + ((long long)b * T_ + (tg0 + 8)) * O_);
                __builtin_nontemporal_store(acc1, &o1[o4]);
            }
            if (nr > 2) {
                v4f* o2 = (v4f*)(out + ((long long)b * T_ + (tg0 + 16)) * O_);
                __builtin_nontemporal_store(acc2, &o2[o4]);
            }
            if (nr > 3) {
                v4f* o3 = (v4f*)(out + ((long long)b * T_ + (tg0 + 24)) * O_);
                __builtin_nontemporal_store(acc3, &o3[o4]);
            }
        }
    }
}

// ---------------------------------------------------------------------------
extern "C" void kernel_launch(void* const* d_in, const int* in_sizes, int n_in,
                              void* d_out, int out_size, void* d_ws, size_t ws_size,
                              hipStream_t stream) {
    const float* tokens  = (const float*)d_in[0];
    const float* w_gate  = (const float*)d_in[1];
    const float* lora_a  = (const float*)d_in[2];
    const float* lora_b  = (const float*)d_in[3];
    const float* scaling = (const float*)d_in[4];
    float* out = (float*)d_out;

    pool_partial<<<dim3(4, 128), 192, 0, stream>>>(tokens, out);
    route<<<128, 256, 0, stream>>>(out, w_gate, out);
    fused_lora<<<dim3(4, 128), 512, 0, stream>>>(tokens, lora_a, lora_b, scaling, out, out);
}

// Round 5
// 333.035 us; speedup vs baseline: 1.9390x; 1.0161x over previous
//
#include <hip/hip_runtime.h>

typedef float v4f __attribute__((ext_vector_type(4)));

// Problem constants
#define B_ 128
#define T_ 197
#define D_ 768
#define E_ 8
#define R_ 8
#define O_ 2304

// d_out flat layout (fp32 elements), in reference return order
#define NWU      (128LL * 197LL * 2304LL)      // weighted_update
#define OFF_RL   (NWU)                          // router_logits: 128*8
#define OFF_SEL  (OFF_RL + 1024LL)              // selected_experts: 128 (as float)
#define OFF_EW   (OFF_SEL + 128LL)              // expert_weights: 128*8
#define OFF_IMP  (OFF_EW + 1024LL)              // importance: 8
#define OFF_LOAD (OFF_IMP + 8LL)                // load: 8

// ---------------------------------------------------------------------------
// Kernel 1: partial token sums over T-chunks, float4-vectorized.
// partials live in the WU region of d_out (consumed by `route` before
// fused_lora overwrites the region).  part[(b*4+c)*768 + d]
// Also zero-inits the importance/load accumulators (16 floats).
// ---------------------------------------------------------------------------
__global__ void pool_partial(const float* __restrict__ tokens,
                             float* __restrict__ out) {
    int c   = blockIdx.x;          // 0..3
    int b   = blockIdx.y;          // 0..127
    int tid = threadIdx.x;         // 0..191  (float4 column)
    if (c == 0 && b == 0 && tid < 16) out[OFF_IMP + tid] = 0.0f;
    int t0 = c * 50;
    int t1 = t0 + 50; if (t1 > T_) t1 = T_;
    const float4* tp = (const float4*)(tokens + (long long)b * T_ * D_);
    float4 acc; acc.x = 0.f; acc.y = 0.f; acc.z = 0.f; acc.w = 0.f;
    for (int t = t0; t < t1; ++t) {
        float4 v = tp[t * 192 + tid];
        acc.x += v.x; acc.y += v.y; acc.z += v.z; acc.w += v.w;
    }
    ((float4*)out)[(long long)(b * 4 + c) * 192 + tid] = acc;
}

// ---------------------------------------------------------------------------
// Kernel 2: routing + stats.  One block per batch row.
// stats (importance/load) folded in via device-scope atomicAdd.
// ---------------------------------------------------------------------------
__global__ void route(const float* __restrict__ part,
                      const float* __restrict__ w_gate,
                      float* __restrict__ out) {
    __shared__ float pooled[768];
    __shared__ float psum[64];
    __shared__ float logits[8];
    __shared__ int   sel_s;
    __shared__ float top1_s;
    __shared__ float m_s, inv_s;

    int b   = blockIdx.x;
    int tid = threadIdx.x;

    #pragma unroll
    for (int j = 0; j < 3; ++j) {
        int d = tid + j * 256;
        float s = part[(long long)(b * 4 + 0) * D_ + d]
                + part[(long long)(b * 4 + 1) * D_ + d]
                + part[(long long)(b * 4 + 2) * D_ + d]
                + part[(long long)(b * 4 + 3) * D_ + d];
        pooled[d] = s * (1.0f / 197.0f);
    }
    __syncthreads();

    if (tid < 64) {
        int e = tid & 7;
        int p = tid >> 3;
        float s = 0.f;
        int d0 = p * 96;
        for (int d = d0; d < d0 + 96; ++d) s += pooled[d] * w_gate[d * 8 + e];
        psum[tid] = s;
    }
    __syncthreads();

    if (tid < 8) {
        float s = 0.f;
        #pragma unroll
        for (int p = 0; p < 8; ++p) s += psum[p * 8 + tid];
        logits[tid] = s;
        out[OFF_RL + (long long)b * 8 + tid] = s;
    }
    __syncthreads();

    if (tid == 0) {
        float m = logits[0];
        int sel = 0;
        #pragma unroll
        for (int e = 1; e < 8; ++e)
            if (logits[e] > m) { m = logits[e]; sel = e; }   // first max wins
        float den = 0.f;
        #pragma unroll
        for (int e = 0; e < 8; ++e) den += expf(logits[e] - m);
        float t1v = 1.0f / den;
        sel_s  = sel;
        top1_s = t1v;
        m_s    = m;
        inv_s  = t1v;
        out[OFF_SEL + b] = (float)sel;
        atomicAdd(&out[OFF_IMP + sel], t1v);     // importance[sel] += top1
    }
    __syncthreads();

    if (tid < 8) {
        out[OFF_EW + (long long)b * 8 + tid] = (tid == sel_s) ? top1_s : 0.0f;
        // load[e] += softmax(logits)[e]
        atomicAdd(&out[OFF_LOAD + tid], expf(logits[tid] - m_s) * inv_s);
    }
}

// ---------------------------------------------------------------------------
// Kernel 3: fused  h = (tokens @ A[sel]) * gs  →  regs  →  wu = h @ Bw[sel].
//
// Round-5 polish on the round-4 structure (which matched prediction):
//  - Grid (2,128) = 256 blocks = exactly 1 block/CU: each CU stages the
//    96 KB (Bw 72 + As 24) ONCE instead of twice, and the 99/98 row split
//    is better balanced than the 50/50/50/47 chunks (every wave gets
//    12-13 rows instead of a ragged 5-6-row tail).
//  - All round-4 invariants frozen: As+Bw co-resident in LDS (no overlay,
//    no phase barrier), h in registers via __shfl_xor butterfly (all lanes
//    hold the sums), per-wave 4-row pipeline interleaving token reads with
//    NT WU stores so both HBM directions stay busy.
//  - Round-3 lesson kept: A must NOT live in registers (spills at the
//    128-VGPR cap → 368 MB scratch FETCH).
//  - Round-2 lesson kept: Bw must NOT be re-read from global per pass
//    (+295 MB FETCH, L2 thrash under streaming pressure).
// ---------------------------------------------------------------------------
__global__ void __launch_bounds__(512, 1)
fused_lora(const float* __restrict__ tokens,
           const float* __restrict__ lora_a,
           const float* __restrict__ lora_b,
           const float* __restrict__ scaling,
           const float* __restrict__ outc,
           float* __restrict__ out) {
    __shared__ __align__(16) float Bw_s[8 * 2304];   // 72 KB
    __shared__ __align__(16) float As[8 * 768];      // 24 KB, transposed A

    int half  = blockIdx.x;        // 0..1
    int b     = blockIdx.y;        // 0..127
    int tid   = threadIdx.x;       // 0..511
    int lane  = tid & 63;
    int wave  = tid >> 6;          // 0..7

    int   sel  = (int)outc[OFF_SEL + b];
    float top1 = outc[OFF_EW + (long long)b * 8 + sel];
    float gs   = scaling[sel] * top1;

    // ---- Stage Bw[sel] (72 KB) into LDS, coalesced.
    const float4* Bw4g = (const float4*)(lora_b + (long long)sel * 8 * 2304);
    float4*       Bw4s = (float4*)Bw_s;
    for (int i = tid; i < 4608; i += 512) Bw4s[i] = Bw4g[i];

    // ---- Stage A[sel] ([d][r] layout) transposed into As[r][d].
    const float4* A4 = (const float4*)(lora_a + (long long)sel * 768 * 8);
    for (int f = tid; f < 1536; f += 512) {
        float4 g = A4[f];
        int d  = f >> 1;
        int r0 = (f & 1) * 4;
        As[(r0 + 0) * 768 + d] = g.x;
        As[(r0 + 1) * 768 + d] = g.y;
        As[(r0 + 2) * 768 + d] = g.z;
        As[(r0 + 3) * 768 + d] = g.w;
    }
    __syncthreads();   // only barrier in the kernel

    int t0 = half * 99;
    int t1 = t0 + 99; if (t1 > T_) t1 = T_;    // 99 rows / 98 rows

    // Wave w owns rows t0+w, t0+w+8, ...  Process 4 at a time (stride 8).
    for (int tg0 = t0 + wave; tg0 < t1; tg0 += 32) {
        int nr = (t1 - tg0 + 7) >> 3;          // valid rows in this group
        if (nr > 4) nr = 4;                    // wave-uniform

        // ---- h for up to 4 rows; butterfly gives every lane the sums.
        float hreg[4][8];
        #pragma unroll
        for (int r = 0; r < 4; ++r) {
            if (r < nr) {   // wave-uniform: shuffles safe inside
                int t = tg0 + 8 * r;
                const float4* tok4 =
                    (const float4*)(tokens + ((long long)b * T_ + t) * D_);
                float acc[8];
                #pragma unroll
                for (int j = 0; j < 8; ++j) acc[j] = 0.f;
                #pragma unroll
                for (int k = 0; k < 3; ++k) {
                    int d4 = lane + 64 * k;
                    float4 tv = tok4[d4];
                    #pragma unroll
                    for (int j = 0; j < 8; ++j) {
                        v4f ar = *(const v4f*)(As + j * 768 + d4 * 4);
                        acc[j] += tv.x * ar.x + tv.y * ar.y
                                + tv.z * ar.z + tv.w * ar.w;
                    }
                }
                #pragma unroll
                for (int off = 32; off > 0; off >>= 1) {
                    #pragma unroll
                    for (int j = 0; j < 8; ++j)
                        acc[j] += __shfl_xor(acc[j], off, 64);
                }
                #pragma unroll
                for (int j = 0; j < 8; ++j) hreg[r][j] = acc[j] * gs;
            }
        }

        // ---- WU for the same rows: one pass over Bw in LDS, 4 rows deep.
        #pragma unroll
        for (int k = 0; k < 9; ++k) {
            int o4 = lane + 64 * k;
            v4f acc0, acc1, acc2, acc3;
            acc0.x = 0.f; acc0.y = 0.f; acc0.z = 0.f; acc0.w = 0.f;
            acc1 = acc0; acc2 = acc0; acc3 = acc0;
            #pragma unroll
            for (int j = 0; j < 8; ++j) {
                v4f bv = ((const v4f*)Bw_s)[j * 576 + o4];
                acc0 += hreg[0][j] * bv;
                acc1 += hreg[1][j] * bv;
                acc2 += hreg[2][j] * bv;
                acc3 += hreg[3][j] * bv;
            }
            {
                v4f* o0 = (v4f*)(out + ((long long)b * T_ + (tg0 + 0)) * O_);
                __builtin_nontemporal_store(acc0, &o0[o4]);
            }
            if (nr > 1) {
                v4f* o1 = (v4f*)(out + ((long long)b * T_ + (tg0 + 8)) * O_);
                __builtin_nontemporal_store(acc1, &o1[o4]);
            }
            if (nr > 2) {
                v4f* o2 = (v4f*)(out + ((long long)b * T_ + (tg0 + 16)) * O_);
                __builtin_nontemporal_store(acc2, &o2[o4]);
            }
            if (nr > 3) {
                v4f* o3 = (v4f*)(out + ((long long)b * T_ + (tg0 + 24)) * O_);
                __builtin_nontemporal_store(acc3, &o3[o4]);
            }
        }
    }
}

// ---------------------------------------------------------------------------
extern "C" void kernel_launch(void* const* d_in, const int* in_sizes, int n_in,
                              void* d_out, int out_size, void* d_ws, size_t ws_size,
                              hipStream_t stream) {
    const float* tokens  = (const float*)d_in[0];
    const float* w_gate  = (const float*)d_in[1];
    const float* lora_a  = (const float*)d_in[2];
    const float* lora_b  = (const float*)d_in[3];
    const float* scaling = (const float*)d_in[4];
    float* out = (float*)d_out;

    pool_partial<<<dim3(4, 128), 192, 0, stream>>>(tokens, out);
    route<<<128, 256, 0, stream>>>(out, w_gate, out);
    fused_lora<<<dim3(2, 128), 512, 0, stream>>>(tokens, lora_a, lora_b, scaling, out, out);
}